// Round 4
// baseline (416.714 us; speedup 1.0000x reference)
//
#include <hip/hip_runtime.h>
#include <stdint.h>

#define DIM 768
#define HDIM 3072

typedef unsigned short u16;
typedef unsigned char u8;
typedef __bf16 bf16x8 __attribute__((ext_vector_type(8)));
typedef __bf16 bf16x4 __attribute__((ext_vector_type(4)));
typedef float f32x4 __attribute__((ext_vector_type(4)));
typedef float f32x16 __attribute__((ext_vector_type(16)));
typedef int i32x8 __attribute__((ext_vector_type(8)));

__device__ __forceinline__ float b2f(u16 u) {
    union { unsigned i; float f; } v; v.i = ((unsigned)u) << 16; return v.f;
}
__device__ __forceinline__ u16 f2b(float f) {
    union { float f; unsigned i; } v; v.f = f;
    unsigned r = (v.i + 0x7FFFu + ((v.i >> 16) & 1u)) >> 16;
    return (u16)r;
}
__device__ __forceinline__ unsigned pack2b(float a, float b) {
    return (unsigned)f2b(a) | ((unsigned)f2b(b) << 16);
}
// tanh-form GELU via v_exp_f32 / v_rcp_f32 (max abs err vs exact ~1e-3)
__device__ __forceinline__ float gelu_f(float v) {
    float u = v * (1.5957691216f + 0.07135481627f * v * v);
    float e = __builtin_amdgcn_exp2f(-1.442695041f * u);
    return v * __builtin_amdgcn_rcpf(1.0f + e);
}
__device__ __forceinline__ void gl_lds16(const void* g, void* l) {
    __builtin_amdgcn_global_load_lds(
        (__attribute__((address_space(1))) void*)(g),
        (__attribute__((address_space(3))) void*)(l), 16, 0, 0);
}

// ---------- fp32 -> bf16 convert ----------
__global__ __launch_bounds__(256) void cvt_bf16(const float4* __restrict__ s,
                                                ushort4* __restrict__ d, int n4) {
    int i = blockIdx.x * 256 + threadIdx.x;
    if (i < n4) {
        float4 v = s[i];
        ushort4 o;
        o.x = f2b(v.x); o.y = f2b(v.y); o.z = f2b(v.z); o.w = f2b(v.w);
        d[i] = o;
    }
}

// ---------- fp32 -> fp8 e4m3 convert (4 floats -> 1 dword) ----------
__global__ __launch_bounds__(256) void cvt_fp8(const float4* __restrict__ s,
                                               unsigned* __restrict__ d, int n4) {
    int i = blockIdx.x * 256 + threadIdx.x;
    if (i < n4) {
        float4 v = s[i];
        int p = __builtin_amdgcn_cvt_pk_fp8_f32(v.x, v.y, 0, false);
        p = __builtin_amdgcn_cvt_pk_fp8_f32(v.z, v.w, p, true);
        d[i] = (unsigned)p;
    }
}

__global__ void pack_bias3(const float* __restrict__ a, const float* __restrict__ b,
                           const float* __restrict__ c, float* __restrict__ o) {
    int i = blockIdx.x * 256 + threadIdx.x;
    if (i < DIM) { o[i] = a[i]; o[i + DIM] = b[i]; o[i + 2 * DIM] = c[i]; }
}

// ---------- LayerNorm (ddof=1, eps on std), wave per row, fp8 output ----------
__global__ __launch_bounds__(256) void ln_rows_f8(const float* __restrict__ x, u8* __restrict__ xn,
                                                  const float* __restrict__ g, const float* __restrict__ b) {
    int row = blockIdx.x * 4 + (threadIdx.x >> 6);
    int lane = threadIdx.x & 63;
    const float* xr = x + (size_t)row * DIM + lane * 12;
    float v[12];
#pragma unroll
    for (int i = 0; i < 3; ++i) {
        float4 t = ((const float4*)xr)[i];
        v[i * 4 + 0] = t.x; v[i * 4 + 1] = t.y; v[i * 4 + 2] = t.z; v[i * 4 + 3] = t.w;
    }
    float s = 0.f, ss = 0.f;
#pragma unroll
    for (int i = 0; i < 12; ++i) { s += v[i]; ss += v[i] * v[i]; }
#pragma unroll
    for (int o = 32; o; o >>= 1) { s += __shfl_xor(s, o); ss += __shfl_xor(ss, o); }
    float mean = s * (1.f / DIM);
    float var = (ss - (float)DIM * mean * mean) * (1.f / (DIM - 1));
    float denom = sqrtf(var) + 1e-6f;
    float sc = g[0] / denom, bb = b[0] - mean * sc;
    unsigned* outp = (unsigned*)(xn + (size_t)row * DIM + lane * 12);
#pragma unroll
    for (int i = 0; i < 3; ++i) {
        int p = __builtin_amdgcn_cvt_pk_fp8_f32(v[i * 4 + 0] * sc + bb, v[i * 4 + 1] * sc + bb, 0, false);
        p = __builtin_amdgcn_cvt_pk_fp8_f32(v[i * 4 + 2] * sc + bb, v[i * 4 + 3] * sc + bb, p, true);
        outp[i] = (unsigned)p;
    }
}

// ---------- fp8 GEMM: C[M,N] = A[M,K] @ B[N,K]^T, MX MFMA w/ unit scales ----------
// BK=128, 128x128 tile. mfma(B,A) => C^T frag layout: lane holds one row,
// 4 consecutive cols per reg-quad -> packed vector stores.
// EPI 0: acc+bias -> bf16 (dwordx2 stores)   (QKV)
// EPI 2: acc+bias+resid -> f32 (dwordx4)     (MLP down + residual)
template <int EPI, int N, int K>
__global__ __launch_bounds__(256)
void gemm_f8(const u8* __restrict__ A, const u8* __restrict__ B,
             const float* __restrict__ bias, const float* __restrict__ resid,
             u16* __restrict__ Cb, float* __restrict__ Cf) {
    __shared__ __align__(16) u8 As[128 * 128];
    __shared__ __align__(16) u8 Bs[128 * 128];
    const int tid = threadIdx.x, lane = tid & 63, wave = tid >> 6;
    const int row0 = blockIdx.x * 128, col0 = blockIdx.y * 128;
    const int wm = (wave >> 1) * 64, wn = (wave & 1) * 64;
    f32x16 acc[2][2] = {};

    const int srow = lane >> 3;
    const int schunk = ((lane & 7) ^ srow) * 16;
    const u8* Ag = A + (size_t)(row0 + wave * 8 + srow) * K + schunk;
    const u8* Bg = B + (size_t)(col0 + wave * 8 + srow) * K + schunk;
    const size_t s32 = (size_t)32 * K;
    u8* AsW = As + wave * 1024;
    u8* BsW = Bs + wave * 1024;

    const int r31 = lane & 31, khalf = lane >> 5;

    for (int kb = 0; kb < K; kb += 128) {
#pragma unroll
        for (int i = 0; i < 4; ++i) {
            gl_lds16(Ag + i * s32, AsW + i * 4096);
            gl_lds16(Bg + i * s32, BsW + i * 4096);
        }
        Ag += 128; Bg += 128;
        __syncthreads();
#pragma unroll
        for (int ks = 0; ks < 2; ++ks) {
            const int c0 = ks * 4 + khalf * 2;  // 16B chunk index (even)
            union { i32x8 v; uint4 q[2]; } af[2], bfr[2];
#pragma unroll
            for (int ib = 0; ib < 2; ++ib) {
                const int r = wm + ib * 32 + r31;
                const u8* base = As + r * 128;
                const int x7 = (r & 7);
                af[ib].q[0] = *(const uint4*)(base + ((c0 ^ x7) * 16));
                af[ib].q[1] = *(const uint4*)(base + (((c0 + 1) ^ x7) * 16));
            }
#pragma unroll
            for (int jb = 0; jb < 2; ++jb) {
                const int r = wn + jb * 32 + r31;
                const u8* base = Bs + r * 128;
                const int x7 = (r & 7);
                bfr[jb].q[0] = *(const uint4*)(base + ((c0 ^ x7) * 16));
                bfr[jb].q[1] = *(const uint4*)(base + (((c0 + 1) ^ x7) * 16));
            }
#pragma unroll
            for (int ib = 0; ib < 2; ++ib)
#pragma unroll
                for (int jb = 0; jb < 2; ++jb)
                    acc[ib][jb] = __builtin_amdgcn_mfma_scale_f32_32x32x64_f8f6f4(
                        bfr[jb].v, af[ib].v, acc[ib][jb], 0, 0,
                        0, 0x7F7F7F7F, 0, 0x7F7F7F7F);  // unit E8M0 scales
        }
        __syncthreads();
    }
    // C^T frag: row = wm+ib*32+r31 (lane), col = wn+jb*32+8*(reg>>2)+4*khalf+(reg&3)
#pragma unroll
    for (int ib = 0; ib < 2; ++ib) {
        const int row = row0 + wm + ib * 32 + r31;
#pragma unroll
        for (int jb = 0; jb < 2; ++jb) {
#pragma unroll
            for (int gq = 0; gq < 4; ++gq) {
                const int cb = col0 + wn + jb * 32 + gq * 8 + 4 * khalf;
                float4 bv = *(const float4*)(bias + cb);
                float v0 = acc[ib][jb][gq * 4 + 0] + bv.x;
                float v1 = acc[ib][jb][gq * 4 + 1] + bv.y;
                float v2 = acc[ib][jb][gq * 4 + 2] + bv.z;
                float v3 = acc[ib][jb][gq * 4 + 3] + bv.w;
                const size_t idx = (size_t)row * N + cb;
                if (EPI == 2) {
                    float4 rv = *(const float4*)(resid + idx);
                    float4 o; o.x = v0 + rv.x; o.y = v1 + rv.y; o.z = v2 + rv.z; o.w = v3 + rv.w;
                    *(float4*)(Cf + idx) = o;
                } else {
                    uint2 o; o.x = pack2b(v0, v1); o.y = pack2b(v2, v3);
                    *(uint2*)(Cb + idx) = o;
                }
            }
        }
    }
}

// ---------- bf16 GEMM (MLP up): gelu epilogue, fp8 packed-dword output ----------
template <int N, int K>
__global__ __launch_bounds__(256)
void gemm_up(const u16* __restrict__ A, const u16* __restrict__ B,
             const float* __restrict__ bias, u8* __restrict__ C8) {
    __shared__ __align__(16) u16 As[128 * 64];
    __shared__ __align__(16) u16 Bs[128 * 64];
    const int tid = threadIdx.x;
    const int row0 = blockIdx.x * 128, col0 = blockIdx.y * 128;
    const int lane = tid & 63, wave = tid >> 6;
    const int wm = (wave >> 1) * 64, wn = (wave & 1) * 64;
    const int la = lane & 15, qd = lane >> 4;
    f32x4 acc[4][4] = {};

    const int srow = lane >> 3;
    const int schunk = (lane & 7) ^ srow;
    const u16* Ag = A + (size_t)(row0 + wave * 8 + srow) * K + schunk * 8;
    const u16* Bg = B + (size_t)(col0 + wave * 8 + srow) * K + schunk * 8;
    const size_t s32 = (size_t)32 * K;
    u16* AsW = &As[wave * 512];
    u16* BsW = &Bs[wave * 512];
    const int x7 = la & 7;

    for (int kb = 0; kb < K; kb += 64) {
#pragma unroll
        for (int i = 0; i < 4; ++i) {
            gl_lds16(Ag + i * s32, AsW + i * 2048);
            gl_lds16(Bg + i * s32, BsW + i * 2048);
        }
        Ag += 64; Bg += 64;
        __syncthreads();
#pragma unroll
        for (int ks = 0; ks < 2; ++ks) {
            const int cp = ((ks * 4 + qd) ^ x7) * 8;
            bf16x8 af[4], bfr[4];
#pragma unroll
            for (int i = 0; i < 4; ++i)
                af[i] = *(const bf16x8*)(&As[(wm + i * 16 + la) * 64 + cp]);
#pragma unroll
            for (int j = 0; j < 4; ++j)
                bfr[j] = *(const bf16x8*)(&Bs[(wn + j * 16 + la) * 64 + cp]);
#pragma unroll
            for (int i = 0; i < 4; ++i)
#pragma unroll
                for (int j = 0; j < 4; ++j)
                    acc[i][j] = __builtin_amdgcn_mfma_f32_16x16x32_bf16(bfr[j], af[i], acc[i][j], 0, 0, 0);
        }
        __syncthreads();
    }
    // C^T frag: row = wm+i*16+la, col = wn+j*16+qd*4+reg
#pragma unroll
    for (int i = 0; i < 4; ++i) {
        const int row = row0 + wm + i * 16 + la;
#pragma unroll
        for (int j = 0; j < 4; ++j) {
            const int cb = col0 + wn + j * 16 + qd * 4;
            float4 bv = *(const float4*)(bias + cb);
            float v0 = gelu_f(acc[i][j][0] + bv.x);
            float v1 = gelu_f(acc[i][j][1] + bv.y);
            float v2 = gelu_f(acc[i][j][2] + bv.z);
            float v3 = gelu_f(acc[i][j][3] + bv.w);
            int p = __builtin_amdgcn_cvt_pk_fp8_f32(v0, v1, 0, false);
            p = __builtin_amdgcn_cvt_pk_fp8_f32(v2, v3, p, true);
            *(unsigned*)(C8 + (size_t)row * N + cb) = (unsigned)p;
        }
    }
}

// ---------- attention (8-token groups) + residual + LN2, vectorized LDS ----------
__global__ __launch_bounds__(256)
void attn_ln(const u16* __restrict__ qkv, const float* __restrict__ x,
             float* __restrict__ x1, u16* __restrict__ xn2,
             const float* __restrict__ g, const float* __restrict__ b) {
    __shared__ __align__(16) u16 sq[8 * 2304];
    __shared__ float sw[64];
    const int tid = threadIdx.x;
    const size_t gbase = (size_t)blockIdx.x * (8 * 2304);
    const uint4* src = (const uint4*)(qkv + gbase);
    uint4* dst = (uint4*)sq;
#pragma unroll
    for (int i = 0; i < 9; ++i) dst[tid + i * 256] = src[tid + i * 256];
    __syncthreads();
    const int wave = tid >> 6, lane = tid & 63;
#pragma unroll 2
    for (int p = wave * 16; p < wave * 16 + 16; ++p) {
        const u16* qr = sq + (p >> 3) * 2304;
        const u16* kr = sq + (p & 7) * 2304 + 768;
        bf16x8 qa = *(const bf16x8*)(qr + lane * 8);
        bf16x8 ka = *(const bf16x8*)(kr + lane * 8);
        bf16x4 qb = *(const bf16x4*)(qr + 512 + lane * 4);
        bf16x4 kb = *(const bf16x4*)(kr + 512 + lane * 4);
        float s = 0.f;
#pragma unroll
        for (int i = 0; i < 8; ++i) s += (float)qa[i] * (float)ka[i];
#pragma unroll
        for (int i = 0; i < 4; ++i) s += (float)qb[i] * (float)kb[i];
#pragma unroll
        for (int o = 32; o; o >>= 1) s += __shfl_xor(s, o);
        if (lane == 0) sw[p] = s;
    }
    __syncthreads();
    if (tid < 8) {
        const float scl = 0.03608439182435161f; // 1/sqrt(768)
        float e[8]; float m = -1e30f;
#pragma unroll
        for (int j = 0; j < 8; ++j) m = fmaxf(m, sw[tid * 8 + j]);
        float sum = 0.f;
#pragma unroll
        for (int j = 0; j < 8; ++j) { e[j] = expf((sw[tid * 8 + j] - m) * scl); sum += e[j]; }
        float inv = 1.f / sum;
#pragma unroll
        for (int j = 0; j < 8; ++j) sw[tid * 8 + j] = e[j] * inv;
    }
    __syncthreads();
    const int h = tid >> 5, li = tid & 31;
    float w[8];
#pragma unroll
    for (int kk = 0; kk < 8; ++kk) w[kk] = sw[h * 8 + kk];
    const size_t trow = (size_t)blockIdx.x * 8 + h;
    const float* xr = x + trow * DIM;
    float* x1r = x1 + trow * DIM;
    float xv[24], s = 0.f, ss = 0.f;
#pragma unroll
    for (int wd = 0; wd < 3; ++wd) {
        const int d0 = wd * 256 + li * 8;
        float o[8] = {};
#pragma unroll
        for (int kk = 0; kk < 8; ++kk) {
            bf16x8 vv = *(const bf16x8*)(sq + kk * 2304 + 1536 + d0);
#pragma unroll
            for (int e = 0; e < 8; ++e) o[e] += w[kk] * (float)vv[e];
        }
        float4 xa = *(const float4*)(xr + d0);
        float4 xb = *(const float4*)(xr + d0 + 4);
        float vals[8] = { o[0] + xa.x, o[1] + xa.y, o[2] + xa.z, o[3] + xa.w,
                          o[4] + xb.x, o[5] + xb.y, o[6] + xb.z, o[7] + xb.w };
        float4 w0, w1;
        w0.x = vals[0]; w0.y = vals[1]; w0.z = vals[2]; w0.w = vals[3];
        w1.x = vals[4]; w1.y = vals[5]; w1.z = vals[6]; w1.w = vals[7];
        *(float4*)(x1r + d0) = w0;
        *(float4*)(x1r + d0 + 4) = w1;
#pragma unroll
        for (int e = 0; e < 8; ++e) {
            xv[wd * 8 + e] = vals[e];
            s += vals[e]; ss += vals[e] * vals[e];
        }
    }
#pragma unroll
    for (int o2 = 16; o2; o2 >>= 1) { s += __shfl_xor(s, o2); ss += __shfl_xor(ss, o2); }
    float mean = s * (1.f / 768.f);
    float var = (ss - 768.f * mean * mean) * (1.f / 767.f);
    float denom = sqrtf(var) + 1e-6f;
    float sc = g[0] / denom, bb = b[0] - mean * sc;
    u16* xnr = xn2 + trow * DIM;
#pragma unroll
    for (int wd = 0; wd < 3; ++wd) {
        const int d0 = wd * 256 + li * 8;
        uint4 o;
        o.x = pack2b(xv[wd * 8 + 0] * sc + bb, xv[wd * 8 + 1] * sc + bb);
        o.y = pack2b(xv[wd * 8 + 2] * sc + bb, xv[wd * 8 + 3] * sc + bb);
        o.z = pack2b(xv[wd * 8 + 4] * sc + bb, xv[wd * 8 + 5] * sc + bb);
        o.w = pack2b(xv[wd * 8 + 6] * sc + bb, xv[wd * 8 + 7] * sc + bb);
        *(uint4*)(xnr + d0) = o;
    }
}

extern "C" void kernel_launch(void* const* d_in, const int* in_sizes, int n_in,
                              void* d_out, int out_size, void* d_ws, size_t ws_size,
                              hipStream_t stream) {
    (void)n_in; (void)out_size; (void)ws_size;
    const float* x    = (const float*)d_in[0];
    const float* wq_w = (const float*)d_in[1];
    const float* wq_b = (const float*)d_in[2];
    const float* wk_w = (const float*)d_in[3];
    const float* wk_b = (const float*)d_in[4];
    const float* wv_w = (const float*)d_in[5];
    const float* wv_b = (const float*)d_in[6];
    const float* d1_w = (const float*)d_in[7];
    const float* d1_b = (const float*)d_in[8];
    const float* d2_w = (const float*)d_in[9];
    const float* d2_b = (const float*)d_in[10];
    const float* g1 = (const float*)d_in[11];
    const float* b1 = (const float*)d_in[12];
    const float* g2 = (const float*)d_in[13];
    const float* b2 = (const float*)d_in[14];
    float* out = (float*)d_out;
    char* ws = (char*)d_ws;

    const int T = in_sizes[0] / DIM;  // 16384

    // ws layout (bytes):
    u8*    w_qkv8 = (u8*)(ws);                    // [2304][768] fp8    1,769,472
    u16*   w_d1   = (u16*)(ws + 1769472);         // [3072][768] bf16   4,718,592
    u8*    w_d28  = (u8*)(ws + 6488064);          // [768][3072] fp8    2,359,296
    float* b_qkv  = (float*)(ws + 8847360);       // [2304] f32             9,216
    u16*   xn2    = (u16*)(ws + 8856576);         // [T][768] bf16     25,165,824
    float* x1     = (float*)(ws + 34022400);      // [T][768] f32      50,331,648
    u8*    xn1_8  = (u8*)(ws + 34022400);         // [T][768] fp8 — aliases x1 (dead before attn)
    u16*   qkv    = (u16*)(ws + 84354048);        // [T][2304] bf16    75,497,472
    u8*    h8     = (u8*)(ws + 84354048);         // [T][3072] fp8 — aliases qkv (dead after attn)

    cvt_fp8<<<576, 256, 0, stream>>>((const float4*)wq_w, (unsigned*)w_qkv8, 147456);
    cvt_fp8<<<576, 256, 0, stream>>>((const float4*)wk_w, (unsigned*)(w_qkv8 + 589824), 147456);
    cvt_fp8<<<576, 256, 0, stream>>>((const float4*)wv_w, (unsigned*)(w_qkv8 + 1179648), 147456);
    cvt_bf16<<<2304, 256, 0, stream>>>((const float4*)d1_w, (ushort4*)w_d1, 589824);
    cvt_fp8<<<2304, 256, 0, stream>>>((const float4*)d2_w, (unsigned*)w_d28, 589824);
    pack_bias3<<<3, 256, 0, stream>>>(wq_b, wk_b, wv_b, b_qkv);

    ln_rows_f8<<<T / 4, 256, 0, stream>>>(x, xn1_8, g1, b1);
    gemm_f8<0, 2304, 768><<<dim3(T / 128, 18), 256, 0, stream>>>(xn1_8, w_qkv8, b_qkv, nullptr, qkv, nullptr);
    attn_ln<<<T / 8, 256, 0, stream>>>(qkv, x, x1, xn2, g2, b2);
    gemm_up<3072, 768><<<dim3(T / 128, 24), 256, 0, stream>>>(xn2, w_d1, d1_b, h8);
    gemm_f8<2, 768, 3072><<<dim3(T / 128, 6), 256, 0, stream>>>(h8, w_d28, d2_b, x1, nullptr, out);
}

// Round 6
// 369.421 us; speedup vs baseline: 1.1280x; 1.1280x over previous
//
#include <hip/hip_runtime.h>
#include <stdint.h>

#define DIM 768
#define HDIM 3072

typedef unsigned short u16;
typedef unsigned char u8;
typedef unsigned int u32;
typedef __bf16 bf16x8 __attribute__((ext_vector_type(8)));
typedef float f32x2 __attribute__((ext_vector_type(2)));
typedef float f32x4 __attribute__((ext_vector_type(4)));
typedef float f32x16 __attribute__((ext_vector_type(16)));
typedef int i32x8 __attribute__((ext_vector_type(8)));

__device__ __forceinline__ u16 f2b(float f) {
    union { float f; unsigned i; } v; v.f = f;
    unsigned r = (v.i + 0x7FFFu + ((v.i >> 16) & 1u)) >> 16;
    return (u16)r;
}
__device__ __forceinline__ unsigned pack2b(float a, float b) {
    return (unsigned)f2b(a) | ((unsigned)f2b(b) << 16);
}
// tanh-form GELU via v_exp_f32 / v_rcp_f32 (max abs err vs exact ~1e-3)
__device__ __forceinline__ float gelu_f(float v) {
    float u = v * (1.5957691216f + 0.07135481627f * v * v);
    float e = __builtin_amdgcn_exp2f(-1.442695041f * u);
    return v * __builtin_amdgcn_rcpf(1.0f + e);
}
__device__ __forceinline__ void gl_lds16(const void* g, void* l) {
    __builtin_amdgcn_global_load_lds(
        (__attribute__((address_space(1))) void*)(g),
        (__attribute__((address_space(3))) void*)(l), 16, 0, 0);
}

// ---------- fp32 -> bf16 convert ----------
__global__ __launch_bounds__(256) void cvt_bf16(const float4* __restrict__ s,
                                                ushort4* __restrict__ d, int n4) {
    int i = blockIdx.x * 256 + threadIdx.x;
    if (i < n4) {
        float4 v = s[i];
        ushort4 o;
        o.x = f2b(v.x); o.y = f2b(v.y); o.z = f2b(v.z); o.w = f2b(v.w);
        d[i] = o;
    }
}

// ---------- fp32 -> fp8 e4m3 convert (4 floats -> 1 dword) ----------
__global__ __launch_bounds__(256) void cvt_fp8(const float4* __restrict__ s,
                                               unsigned* __restrict__ d, int n4) {
    int i = blockIdx.x * 256 + threadIdx.x;
    if (i < n4) {
        float4 v = s[i];
        int p = __builtin_amdgcn_cvt_pk_fp8_f32(v.x, v.y, 0, false);
        p = __builtin_amdgcn_cvt_pk_fp8_f32(v.z, v.w, p, true);
        d[i] = (unsigned)p;
    }
}

__global__ void pack_bias3(const float* __restrict__ a, const float* __restrict__ b,
                           const float* __restrict__ c, float* __restrict__ o) {
    int i = blockIdx.x * 256 + threadIdx.x;
    if (i < DIM) { o[i] = a[i]; o[i + DIM] = b[i]; o[i + 2 * DIM] = c[i]; }
}

// ---------- LayerNorm (ddof=1, eps on std), wave per row, fp8 output ----------
__global__ __launch_bounds__(256) void ln_rows_f8(const float* __restrict__ x, u8* __restrict__ xn,
                                                  const float* __restrict__ g, const float* __restrict__ b) {
    int row = blockIdx.x * 4 + (threadIdx.x >> 6);
    int lane = threadIdx.x & 63;
    const float* xr = x + (size_t)row * DIM + lane * 12;
    float v[12];
#pragma unroll
    for (int i = 0; i < 3; ++i) {
        float4 t = ((const float4*)xr)[i];
        v[i * 4 + 0] = t.x; v[i * 4 + 1] = t.y; v[i * 4 + 2] = t.z; v[i * 4 + 3] = t.w;
    }
    float s = 0.f, ss = 0.f;
#pragma unroll
    for (int i = 0; i < 12; ++i) { s += v[i]; ss += v[i] * v[i]; }
#pragma unroll
    for (int o = 32; o; o >>= 1) { s += __shfl_xor(s, o); ss += __shfl_xor(ss, o); }
    float mean = s * (1.f / DIM);
    float var = (ss - (float)DIM * mean * mean) * (1.f / (DIM - 1));
    float denom = sqrtf(var) + 1e-6f;
    float sc = g[0] / denom, bb = b[0] - mean * sc;
    unsigned* outp = (unsigned*)(xn + (size_t)row * DIM + lane * 12);
#pragma unroll
    for (int i = 0; i < 3; ++i) {
        int p = __builtin_amdgcn_cvt_pk_fp8_f32(v[i * 4 + 0] * sc + bb, v[i * 4 + 1] * sc + bb, 0, false);
        p = __builtin_amdgcn_cvt_pk_fp8_f32(v[i * 4 + 2] * sc + bb, v[i * 4 + 3] * sc + bb, p, true);
        outp[i] = (unsigned)p;
    }
}

// ---------- fp8 GEMM: C[M,N] = A[M,K] @ B[N,K]^T, MX MFMA w/ unit scales ----------
// BK=128, 128x128 tile, swapped mfma(B,A) -> C^T reg layout; coalesced stores
// via LDS-staged, 4B-XOR-swizzled C tile.
// EPI 0: acc+bias -> fp8 out       (QKV)
// EPI 2: acc+bias+resid -> f32 out (MLP down + residual), 2-pass 32KB staging
template <int EPI, int N, int K>
__global__ __launch_bounds__(256)
void gemm_f8(const u8* __restrict__ A, const u8* __restrict__ B,
             const float* __restrict__ bias, const float* __restrict__ resid,
             u8* __restrict__ Co, float* __restrict__ Cf) {
    __shared__ __align__(16) u8 smem[32768];
    u8* As = smem;
    u8* Bs = smem + 16384;
    const int tid = threadIdx.x, lane = tid & 63, wave = tid >> 6;
    const int row0 = blockIdx.x * 128, col0 = blockIdx.y * 128;
    const int wm = (wave >> 1) * 64, wn = (wave & 1) * 64;
    f32x16 acc[2][2] = {};

    const int srow = lane >> 3;
    const int schunk = ((lane & 7) ^ srow) * 16;
    const u8* Ag = A + (size_t)(row0 + wave * 8 + srow) * K + schunk;
    const u8* Bg = B + (size_t)(col0 + wave * 8 + srow) * K + schunk;
    const size_t s32 = (size_t)32 * K;
    u8* AsW = As + wave * 1024;
    u8* BsW = Bs + wave * 1024;

    const int r31 = lane & 31, khalf = lane >> 5;

    for (int kb = 0; kb < K; kb += 128) {
#pragma unroll
        for (int i = 0; i < 4; ++i) {
            gl_lds16(Ag + i * s32, AsW + i * 4096);
            gl_lds16(Bg + i * s32, BsW + i * 4096);
        }
        Ag += 128; Bg += 128;
        __syncthreads();
#pragma unroll
        for (int ks = 0; ks < 2; ++ks) {
            const int c0 = ks * 4 + khalf * 2;
            union { i32x8 v; uint4 q[2]; } af[2], bfr[2];
#pragma unroll
            for (int ib = 0; ib < 2; ++ib) {
                const int r = wm + ib * 32 + r31;
                const u8* base = As + r * 128;
                const int x7 = (r & 7);
                af[ib].q[0] = *(const uint4*)(base + ((c0 ^ x7) * 16));
                af[ib].q[1] = *(const uint4*)(base + (((c0 + 1) ^ x7) * 16));
            }
#pragma unroll
            for (int jb = 0; jb < 2; ++jb) {
                const int r = wn + jb * 32 + r31;
                const u8* base = Bs + r * 128;
                const int x7 = (r & 7);
                bfr[jb].q[0] = *(const uint4*)(base + ((c0 ^ x7) * 16));
                bfr[jb].q[1] = *(const uint4*)(base + (((c0 + 1) ^ x7) * 16));
            }
#pragma unroll
            for (int ib = 0; ib < 2; ++ib)
#pragma unroll
                for (int jb = 0; jb < 2; ++jb)
                    acc[ib][jb] = __builtin_amdgcn_mfma_scale_f32_32x32x64_f8f6f4(
                        bfr[jb].v, af[ib].v, acc[ib][jb], 0, 0,
                        0, 0x7F7F7F7F, 0, 0x7F7F7F7F);
        }
        __syncthreads();
    }
    // C^T frag: local row = wm+ib*32+r31, local col = wn+jb*32+gq*8+4*khalf+(reg&3)
    if (EPI == 0) {
        // stage packed fp8 tile (128 rows x 128B), dword-XOR swizzle
        u32* Cs = (u32*)smem;
#pragma unroll
        for (int ib = 0; ib < 2; ++ib) {
            const int row = wm + ib * 32 + r31;
            const int rx = row & 31;
#pragma unroll
            for (int jb = 0; jb < 2; ++jb)
#pragma unroll
                for (int gq = 0; gq < 4; ++gq) {
                    const int cb = wn + jb * 32 + gq * 8 + 4 * khalf;
                    float4 bv = *(const float4*)(bias + col0 + cb);
                    float v0 = acc[ib][jb][gq * 4 + 0] + bv.x;
                    float v1 = acc[ib][jb][gq * 4 + 1] + bv.y;
                    float v2 = acc[ib][jb][gq * 4 + 2] + bv.z;
                    float v3 = acc[ib][jb][gq * 4 + 3] + bv.w;
                    int p = __builtin_amdgcn_cvt_pk_fp8_f32(v0, v1, 0, false);
                    p = __builtin_amdgcn_cvt_pk_fp8_f32(v2, v3, p, true);
                    Cs[row * 32 + ((cb >> 2) ^ rx)] = (u32)p;
                }
        }
        __syncthreads();
#pragma unroll
        for (int pr = 0; pr < 4; ++pr) {
            const int r = pr * 32 + (tid >> 3);
            const int rx = r & 31;
            const int dwb = (tid & 7) * 4;
            uint4 o;
            o.x = Cs[r * 32 + ((dwb + 0) ^ rx)];
            o.y = Cs[r * 32 + ((dwb + 1) ^ rx)];
            o.z = Cs[r * 32 + ((dwb + 2) ^ rx)];
            o.w = Cs[r * 32 + ((dwb + 3) ^ rx)];
            *(uint4*)(Co + (size_t)(row0 + r) * N + col0 + dwb * 4) = o;
        }
    } else {
        // fp32 out + resid: 2-pass staging, 64 rows x 128 f32 (32KB), 16B-chunk swizzle
        float* Cs = (float*)smem;
#pragma unroll
        for (int pass = 0; pass < 2; ++pass) {
            const int ss = (wm >> 1) + r31;  // slot row 0..63
            const int sx = ss & 7;
#pragma unroll
            for (int jb = 0; jb < 2; ++jb)
#pragma unroll
                for (int gq = 0; gq < 4; ++gq) {
                    const int cb = wn + jb * 32 + gq * 8 + 4 * khalf;
                    float4 bv = *(const float4*)(bias + col0 + cb);
                    float4 v;
                    v.x = acc[pass][jb][gq * 4 + 0] + bv.x;
                    v.y = acc[pass][jb][gq * 4 + 1] + bv.y;
                    v.z = acc[pass][jb][gq * 4 + 2] + bv.z;
                    v.w = acc[pass][jb][gq * 4 + 3] + bv.w;
                    *(float4*)(Cs + ss * 128 + (((cb >> 2) ^ sx) << 2)) = v;
                }
            __syncthreads();
            const int s = tid >> 2;
            const int grow = row0 + (s >> 5) * 64 + pass * 32 + (s & 31);
#pragma unroll
            for (int k = 0; k < 8; ++k) {
                const int c = k * 4 + (tid & 3);
                float4 v = *(const float4*)(Cs + s * 128 + ((c ^ (s & 7)) << 2));
                const size_t gi = (size_t)grow * N + col0 + c * 4;
                float4 rv = *(const float4*)(resid + gi);
                v.x += rv.x; v.y += rv.y; v.z += rv.z; v.w += rv.w;
                *(float4*)(Cf + gi) = v;
            }
            if (pass == 0) __syncthreads();
        }
    }
}

// ---------- bf16 GEMM (MLP up): gelu epilogue, fp8 out via staged coalesced stores ----------
template <int N, int K>
__global__ __launch_bounds__(256)
void gemm_up(const u16* __restrict__ A, const u16* __restrict__ B,
             const float* __restrict__ bias, u8* __restrict__ C8) {
    __shared__ __align__(16) u16 As[128 * 64];
    __shared__ __align__(16) u16 Bs[128 * 64];
    const int tid = threadIdx.x;
    const int row0 = blockIdx.x * 128, col0 = blockIdx.y * 128;
    const int lane = tid & 63, wave = tid >> 6;
    const int wm = (wave >> 1) * 64, wn = (wave & 1) * 64;
    const int la = lane & 15, qd = lane >> 4;
    f32x4 acc[4][4] = {};

    const int srow = lane >> 3;
    const int schunk = (lane & 7) ^ srow;
    const u16* Ag = A + (size_t)(row0 + wave * 8 + srow) * K + schunk * 8;
    const u16* Bg = B + (size_t)(col0 + wave * 8 + srow) * K + schunk * 8;
    const size_t s32 = (size_t)32 * K;
    u16* AsW = &As[wave * 512];
    u16* BsW = &Bs[wave * 512];
    const int x7 = la & 7;

    for (int kb = 0; kb < K; kb += 64) {
#pragma unroll
        for (int i = 0; i < 4; ++i) {
            gl_lds16(Ag + i * s32, AsW + i * 2048);
            gl_lds16(Bg + i * s32, BsW + i * 2048);
        }
        Ag += 64; Bg += 64;
        __syncthreads();
#pragma unroll
        for (int ks = 0; ks < 2; ++ks) {
            const int cp = ((ks * 4 + qd) ^ x7) * 8;
            bf16x8 af[4], bfr[4];
#pragma unroll
            for (int i = 0; i < 4; ++i)
                af[i] = *(const bf16x8*)(&As[(wm + i * 16 + la) * 64 + cp]);
#pragma unroll
            for (int j = 0; j < 4; ++j)
                bfr[j] = *(const bf16x8*)(&Bs[(wn + j * 16 + la) * 64 + cp]);
#pragma unroll
            for (int i = 0; i < 4; ++i)
#pragma unroll
                for (int j = 0; j < 4; ++j)
                    acc[i][j] = __builtin_amdgcn_mfma_f32_16x16x32_bf16(bfr[j], af[i], acc[i][j], 0, 0, 0);
        }
        __syncthreads();
    }
    // C^T frag: local row = wm+i*16+la, local col = wn+j*16+qd*4+reg
    u32* Cs = (u32*)As;  // 16KB fp8 tile stage
#pragma unroll
    for (int i = 0; i < 4; ++i) {
        const int row = wm + i * 16 + la;
        const int rx = row & 31;
#pragma unroll
        for (int j = 0; j < 4; ++j) {
            const int cb = wn + j * 16 + qd * 4;
            float4 bv = *(const float4*)(bias + col0 + cb);
            float v0 = gelu_f(acc[i][j][0] + bv.x);
            float v1 = gelu_f(acc[i][j][1] + bv.y);
            float v2 = gelu_f(acc[i][j][2] + bv.z);
            float v3 = gelu_f(acc[i][j][3] + bv.w);
            int p = __builtin_amdgcn_cvt_pk_fp8_f32(v0, v1, 0, false);
            p = __builtin_amdgcn_cvt_pk_fp8_f32(v2, v3, p, true);
            Cs[row * 32 + ((cb >> 2) ^ rx)] = (u32)p;
        }
    }
    __syncthreads();
#pragma unroll
    for (int pr = 0; pr < 4; ++pr) {
        const int r = pr * 32 + (tid >> 3);
        const int rx = r & 31;
        const int dwb = (tid & 7) * 4;
        uint4 o;
        o.x = Cs[r * 32 + ((dwb + 0) ^ rx)];
        o.y = Cs[r * 32 + ((dwb + 1) ^ rx)];
        o.z = Cs[r * 32 + ((dwb + 2) ^ rx)];
        o.w = Cs[r * 32 + ((dwb + 3) ^ rx)];
        *(uint4*)(C8 + (size_t)(row0 + r) * N + col0 + dwb * 4) = o;
    }
}

// ---------- attention (8-token groups, fp8 qkv) + residual + LN2 ----------
__global__ __launch_bounds__(256)
void attn_ln(const u8* __restrict__ qkv, const float* __restrict__ x,
             float* __restrict__ x1, u16* __restrict__ xn2,
             const float* __restrict__ g, const float* __restrict__ b) {
    __shared__ __align__(16) u8 sq[8 * 2304];
    __shared__ float sw[64];
    const int tid = threadIdx.x;
    const uint4* src = (const uint4*)(qkv + (size_t)blockIdx.x * (8 * 2304));
    uint4* dst = (uint4*)sq;
#pragma unroll
    for (int i = 0; i < 5; ++i) {
        int idx = tid + i * 256;
        if (idx < 1152) dst[idx] = src[idx];
    }
    __syncthreads();
    const u32* sq32 = (const u32*)sq;
    const int wave = tid >> 6, lane = tid & 63;
#pragma unroll 2
    for (int p = wave * 16; p < wave * 16 + 16; ++p) {
        const u32* qr = sq32 + (p >> 3) * 576 + lane * 3;
        const u32* kr = sq32 + (p & 7) * 576 + 192 + lane * 3;
        float s = 0.f;
#pragma unroll
        for (int i = 0; i < 3; ++i) {
            u32 qd = qr[i], kd = kr[i];
            f32x2 q0 = __builtin_amdgcn_cvt_pk_f32_fp8(qd, false);
            f32x2 q1 = __builtin_amdgcn_cvt_pk_f32_fp8(qd, true);
            f32x2 k0 = __builtin_amdgcn_cvt_pk_f32_fp8(kd, false);
            f32x2 k1 = __builtin_amdgcn_cvt_pk_f32_fp8(kd, true);
            s += q0[0] * k0[0] + q0[1] * k0[1] + q1[0] * k1[0] + q1[1] * k1[1];
        }
#pragma unroll
        for (int o = 32; o; o >>= 1) s += __shfl_xor(s, o);
        if (lane == 0) sw[p] = s;
    }
    __syncthreads();
    if (tid < 8) {
        const float scl = 0.03608439182435161f; // 1/sqrt(768)
        float e[8]; float m = -1e30f;
#pragma unroll
        for (int j = 0; j < 8; ++j) m = fmaxf(m, sw[tid * 8 + j]);
        float sum = 0.f;
#pragma unroll
        for (int j = 0; j < 8; ++j) { e[j] = expf((sw[tid * 8 + j] - m) * scl); sum += e[j]; }
        float inv = 1.f / sum;
#pragma unroll
        for (int j = 0; j < 8; ++j) sw[tid * 8 + j] = e[j] * inv;
    }
    __syncthreads();
    const int h = tid >> 5, li = tid & 31;
    float w[8];
#pragma unroll
    for (int kk = 0; kk < 8; ++kk) w[kk] = sw[h * 8 + kk];
    const size_t trow = (size_t)blockIdx.x * 8 + h;
    const float* xr = x + trow * DIM;
    float* x1r = x1 + trow * DIM;
    float xv[24], s = 0.f, ss = 0.f;
#pragma unroll
    for (int wd = 0; wd < 3; ++wd) {
        const int d0 = wd * 256 + li * 8;
        float o[8] = {};
#pragma unroll
        for (int kk = 0; kk < 8; ++kk) {
            uint2 vv = *(const uint2*)(sq32 + kk * 576 + 384 + wd * 64 + li * 2);
            f32x2 a0 = __builtin_amdgcn_cvt_pk_f32_fp8(vv.x, false);
            f32x2 a1 = __builtin_amdgcn_cvt_pk_f32_fp8(vv.x, true);
            f32x2 a2 = __builtin_amdgcn_cvt_pk_f32_fp8(vv.y, false);
            f32x2 a3 = __builtin_amdgcn_cvt_pk_f32_fp8(vv.y, true);
            o[0] += w[kk] * a0[0]; o[1] += w[kk] * a0[1];
            o[2] += w[kk] * a1[0]; o[3] += w[kk] * a1[1];
            o[4] += w[kk] * a2[0]; o[5] += w[kk] * a2[1];
            o[6] += w[kk] * a3[0]; o[7] += w[kk] * a3[1];
        }
        float4 xa = *(const float4*)(xr + d0);
        float4 xb = *(const float4*)(xr + d0 + 4);
        float vals[8] = { o[0] + xa.x, o[1] + xa.y, o[2] + xa.z, o[3] + xa.w,
                          o[4] + xb.x, o[5] + xb.y, o[6] + xb.z, o[7] + xb.w };
        float4 w0, w1;
        w0.x = vals[0]; w0.y = vals[1]; w0.z = vals[2]; w0.w = vals[3];
        w1.x = vals[4]; w1.y = vals[5]; w1.z = vals[6]; w1.w = vals[7];
        *(float4*)(x1r + d0) = w0;
        *(float4*)(x1r + d0 + 4) = w1;
#pragma unroll
        for (int e = 0; e < 8; ++e) {
            xv[wd * 8 + e] = vals[e];
            s += vals[e]; ss += vals[e] * vals[e];
        }
    }
#pragma unroll
    for (int o2 = 16; o2; o2 >>= 1) { s += __shfl_xor(s, o2); ss += __shfl_xor(ss, o2); }
    float mean = s * (1.f / 768.f);
    float var = (ss - 768.f * mean * mean) * (1.f / 767.f);
    float denom = sqrtf(var) + 1e-6f;
    float sc = g[0] / denom, bb = b[0] - mean * sc;
    u16* xnr = xn2 + trow * DIM;
#pragma unroll
    for (int wd = 0; wd < 3; ++wd) {
        const int d0 = wd * 256 + li * 8;
        uint4 o;
        o.x = pack2b(xv[wd * 8 + 0] * sc + bb, xv[wd * 8 + 1] * sc + bb);
        o.y = pack2b(xv[wd * 8 + 2] * sc + bb, xv[wd * 8 + 3] * sc + bb);
        o.z = pack2b(xv[wd * 8 + 4] * sc + bb, xv[wd * 8 + 5] * sc + bb);
        o.w = pack2b(xv[wd * 8 + 6] * sc + bb, xv[wd * 8 + 7] * sc + bb);
        *(uint4*)(xnr + d0) = o;
    }
}

extern "C" void kernel_launch(void* const* d_in, const int* in_sizes, int n_in,
                              void* d_out, int out_size, void* d_ws, size_t ws_size,
                              hipStream_t stream) {
    (void)n_in; (void)out_size; (void)ws_size;
    const float* x    = (const float*)d_in[0];
    const float* wq_w = (const float*)d_in[1];
    const float* wq_b = (const float*)d_in[2];
    const float* wk_w = (const float*)d_in[3];
    const float* wk_b = (const float*)d_in[4];
    const float* wv_w = (const float*)d_in[5];
    const float* wv_b = (const float*)d_in[6];
    const float* d1_w = (const float*)d_in[7];
    const float* d1_b = (const float*)d_in[8];
    const float* d2_w = (const float*)d_in[9];
    const float* d2_b = (const float*)d_in[10];
    const float* g1 = (const float*)d_in[11];
    const float* b1 = (const float*)d_in[12];
    const float* g2 = (const float*)d_in[13];
    const float* b2 = (const float*)d_in[14];
    float* out = (float*)d_out;
    char* ws = (char*)d_ws;

    const int T = in_sizes[0] / DIM;  // 16384

    // ws layout (bytes):
    u8*    w_qkv8 = (u8*)(ws);                    // [2304][768] fp8    1,769,472
    u16*   w_d1   = (u16*)(ws + 1769472);         // [3072][768] bf16   4,718,592
    u8*    w_d28  = (u8*)(ws + 6488064);          // [768][3072] fp8    2,359,296
    float* b_qkv  = (float*)(ws + 8847360);       // [2304] f32             9,216
    u16*   xn2    = (u16*)(ws + 8856576);         // [T][768] bf16     25,165,824
    float* x1     = (float*)(ws + 34022400);      // [T][768] f32      50,331,648
    u8*    xn1_8  = (u8*)(ws + 34022400);         // [T][768] fp8 — aliases x1 (dead before attn)
    u8*    qkv8   = (u8*)(ws + 84354048);         // [T][2304] fp8     37,748,736
    u8*    h8     = (u8*)(ws + 84354048);         // [T][3072] fp8 — reuses qkv region (dead after attn)

    cvt_fp8<<<576, 256, 0, stream>>>((const float4*)wq_w, (unsigned*)w_qkv8, 147456);
    cvt_fp8<<<576, 256, 0, stream>>>((const float4*)wk_w, (unsigned*)(w_qkv8 + 589824), 147456);
    cvt_fp8<<<576, 256, 0, stream>>>((const float4*)wv_w, (unsigned*)(w_qkv8 + 1179648), 147456);
    cvt_bf16<<<2304, 256, 0, stream>>>((const float4*)d1_w, (ushort4*)w_d1, 589824);
    cvt_fp8<<<2304, 256, 0, stream>>>((const float4*)d2_w, (unsigned*)w_d28, 589824);
    pack_bias3<<<3, 256, 0, stream>>>(wq_b, wk_b, wv_b, b_qkv);

    ln_rows_f8<<<T / 4, 256, 0, stream>>>(x, xn1_8, g1, b1);
    gemm_f8<0, 2304, 768><<<dim3(T / 128, 18), 256, 0, stream>>>(xn1_8, w_qkv8, b_qkv, nullptr, qkv8, nullptr);
    attn_ln<<<T / 8, 256, 0, stream>>>(qkv8, x, x1, xn2, g2, b2);
    gemm_up<3072, 768><<<dim3(T / 128, 24), 256, 0, stream>>>(xn2, w_d1, d1_b, h8);
    gemm_f8<2, 768, 3072><<<dim3(T / 128, 6), 256, 0, stream>>>(h8, w_d28, d2_b, x1, nullptr, out);
}